// Round 5
// baseline (380.748 us; speedup 1.0000x reference)
//
#include <hip/hip_runtime.h>

#define TT   512
#define CH   128
#define HWP  784        // 28*28
#define NSEG 8
#define NOUT 51380224   // 512*128*784

typedef short bf16x8  __attribute__((ext_vector_type(8)));
typedef float f32x4   __attribute__((ext_vector_type(4)));
typedef float f32x16  __attribute__((ext_vector_type(16)));
typedef int   i32x4   __attribute__((ext_vector_type(4)));
typedef unsigned short u16x4 __attribute__((ext_vector_type(4)));

__device__ inline unsigned short f2bf(float f) {
    unsigned u = __builtin_bit_cast(unsigned, f);
    u += 0x7fffu + ((u >> 16) & 1u);          // RNE
    return (unsigned short)(u >> 16);
}

__device__ inline void gld_lds16(const void* g, void* l) {
    __builtin_amdgcn_global_load_lds(
        (const __attribute__((address_space(1))) void*)g,
        (__attribute__((address_space(3))) void*)l, 16, 0, 0);
}

// ---------------------------------------------------------------------------
// Spatial weight repack for 32x32x16 MFMA, frag-major:
// frag (tap, ks, m): lane l = kgrp*32 + (co&31), elems e: ci = ks*16+kgrp*8+e
// dst = (((tap*8 + ks)*4 + m)*64 + l)*8 + e
// ---------------------------------------------------------------------------
__global__ void repack_wsp(const float* __restrict__ w, short* __restrict__ wA) {
    int s = blockIdx.x * 256 + threadIdx.x;
    if (s >= 128 * 128 * 9) return;
    int co = s / 1152, r = s % 1152, ci = r / 9, kh = (r % 9) / 3, kw = r % 3;
    int tap = kh * 3 + kw;
    int m = co >> 5, row = co & 31;
    int ks = ci >> 4, kgrp = (ci >> 3) & 1, e = ci & 7;
    int lane = kgrp * 32 + row;
    int dst = (((tap * 8 + ks) * 4 + m) * 64 + lane) * 8 + e;
    wA[dst] = (short)f2bf(w[s]);
}

// ---------------------------------------------------------------------------
// Temporal weight repack (identity ci order, 16x16x32 frag-major):
// wAt[tap][o>>4][i>>5][(i>>3)&3][o&15][i&7]
// ---------------------------------------------------------------------------
__global__ void repack_wt2(const float* __restrict__ w, short* __restrict__ wAt) {
    int s = blockIdx.x * 256 + threadIdx.x;
    if (s >= 128 * 128 * 3) return;
    int o = s / 384, r = s % 384, i = r / 3, tap = r % 3;
    int dst = tap * 16384 + (o >> 4) * 2048 + (i >> 5) * 512 +
              ((i >> 3) & 3) * 128 + (o & 15) * 8 + (i & 7);
    wAt[dst] = (short)f2bf(w[s]);
}

// ---------------------------------------------------------------------------
// Spatial 3x3 conv via mfma_f32_32x32x16_bf16. grid (4, 512), block 512.
// Block: 8 rows (block 3: 4) x 128 co. LDS window [10 rows][30 st][128 ci]
// bf16, 16B-slot swizzle slot' = slot ^ (st&7) (exactly even bank spread).
// Waves 0..6: one 32-px tile each, 128 co (acc = 4 x f32x16). Wave 7 stages.
// Per (tap,ks): 4 A-frag loads (L1-shared across waves), 1 ds_read_b128,
// 4 MFMAs. Epilogue: per-lane u16x4 stores (L2 merges to full lines).
// ---------------------------------------------------------------------------
__global__ __launch_bounds__(512, 4) void spatial_mfma(
    const float* __restrict__ x, const short* __restrict__ wA,
    const float* __restrict__ b_sp, unsigned short* __restrict__ yT)
{
    __shared__ __align__(16) short xs[300 * 128];   // 76800 B
    char* xsb = (char*)xs;
    const int t = blockIdx.y, blockh = blockIdx.x * 8;
    const int tid = threadIdx.x;

    // ---- zero pad columns: st = r*30 + {0,29}, r = 0..9 ----
    for (int it = 0; it < 3; ++it) {
        int u = it * 512 + tid;
        if (u < 1280) {
            int cp = u & 63, rs = u >> 6;        // rs 0..19
            int st = (rs >> 1) * 30 + (rs & 1) * 29;
            int addr = (st << 8) | ((((cp >> 2) ^ (st & 7)) << 4)) | ((cp & 3) << 2);
            *(unsigned*)(xsb + addr) = 0u;
        }
    }
    // ---- stage x window: lane=cp (conflict-free), wave-uniform st ----
    for (int it = 0; it < 9; ++it) {
        int u = it * 512 + tid;
        if (u < 4480) {
            int cp = u & 63, pq = u >> 6;        // pq 0..69
            int rl = pq / 7, g = pq % 7;
            int rr = blockh - 1 + rl;
            float4 f0 = make_float4(0.f, 0.f, 0.f, 0.f), f1 = f0;
            if (rr >= 0 && rr < 28) {
                const float* p0 = &x[((size_t)(t * CH + 2 * cp)) * HWP + rr * 28 + g * 4];
                f0 = *(const float4*)p0;
                f1 = *(const float4*)(p0 + HWP);
            }
            float a0[4] = {f0.x, f0.y, f0.z, f0.w}, a1[4] = {f1.x, f1.y, f1.z, f1.w};
            int stb = rl * 30 + g * 4 + 1;
#pragma unroll
            for (int j = 0; j < 4; ++j) {
                int st = stb + j;
                unsigned val = (unsigned)f2bf(a0[j]) | ((unsigned)f2bf(a1[j]) << 16);
                int addr = (st << 8) | ((((cp >> 2) ^ (st & 7)) << 4)) | ((cp & 3) << 2);
                *(unsigned*)(xsb + addr) = val;
            }
        }
    }
    __syncthreads();

    const int wid = tid >> 6, l = tid & 63;
    const int l31 = l & 31, bb5 = l >> 5;
    int rows = 28 - blockh; if (rows > 8) rows = 8;
    const int pxcnt = rows * 28;
    const int p0 = wid * 32;
    if (wid >= 7 || p0 >= pxcnt) return;     // wave 7 = stage-only; dead tiles

    const int p = p0 + l31;                   // px within block (may exceed pxcnt)
    const int st0 = (p / 28 + 1) * 30 + (p % 28) + 1;
    const bool pok = (p < pxcnt);

    f32x16 zz = {};
    f32x16 acc0 = zz, acc1 = zz, acc2 = zz, acc3 = zz;

    const bf16x8* wv = (const bf16x8*)wA;

    for (int tap = 0; tap < 9; ++tap) {
        int off = (tap / 3 - 1) * 30 + (tap % 3) - 1;
        int stv = st0 + off;
        int rb = stv << 8;
        int tt = (bb5 ^ (stv & 7)) << 4;
#pragma unroll
        for (int ks = 0; ks < 8; ++ks) {
            int fb = ((tap * 8 + ks) * 4) * 64 + l;
            bf16x8 a0 = wv[fb];
            bf16x8 a1 = wv[fb + 64];
            bf16x8 a2 = wv[fb + 128];
            bf16x8 a3 = wv[fb + 192];
            i32x4 bi = *(const i32x4*)(xsb + (rb | ((ks << 5) ^ tt)));
            bf16x8 bfr = __builtin_bit_cast(bf16x8, bi);
            __builtin_amdgcn_s_setprio(1);
            acc0 = __builtin_amdgcn_mfma_f32_32x32x16_bf16(a0, bfr, acc0, 0, 0, 0);
            acc1 = __builtin_amdgcn_mfma_f32_32x32x16_bf16(a1, bfr, acc1, 0, 0, 0);
            acc2 = __builtin_amdgcn_mfma_f32_32x32x16_bf16(a2, bfr, acc2, 0, 0, 0);
            acc3 = __builtin_amdgcn_mfma_f32_32x32x16_bf16(a3, bfr, acc3, 0, 0, 0);
            __builtin_amdgcn_s_setprio(0);
        }
    }

    // ---- epilogue: +b_sp, u16x4 per (m, r2); 2 lanes/px cover full 256B ----
    const size_t rowbase = ((size_t)t * HWP + blockh * 28 + p) * CH;
    f32x16 accs[4] = {acc0, acc1, acc2, acc3};
#pragma unroll
    for (int m = 0; m < 4; ++m) {
#pragma unroll
        for (int r2 = 0; r2 < 4; ++r2) {
            int cb = m * 32 + 8 * r2 + 4 * bb5;
            float4 bs = *(const float4*)&b_sp[cb];
            float bsa[4] = {bs.x, bs.y, bs.z, bs.w};
            u16x4 pk;
#pragma unroll
            for (int q = 0; q < 4; ++q)
                pk[q] = f2bf(accs[m][r2 * 4 + q] + bsa[q]);
            if (pok) *(u16x4*)&yT[rowbase + cb] = pk;
        }
    }
}

// ---------------------------------------------------------------------------
// Ragged temporal conv: 4-wave blocks, async LDS-staged B, double-buffered.
// grid (7, 512), block 256. (unchanged)
// ---------------------------------------------------------------------------
__global__ __launch_bounds__(256, 4) void temporal_mfma(
    const unsigned short* __restrict__ yT, const short* __restrict__ wAt,
    const float* __restrict__ b_t, const float* __restrict__ alpha,
    const float* __restrict__ x, const int* __restrict__ vid_lens,
    float* __restrict__ out)
{
    __shared__ __align__(16) char ldsT[29696];   // 2x14336 stage | 4x7424 epi

    const int chunk = blockIdx.x, t = blockIdx.y;
    const int tid = threadIdx.x, wid = tid >> 6, l = tid & 63;
    const int l15 = l & 15, kgrp = l >> 4;
    const int sx = l15 & 7;

    bool isS = false, isE = false;
    {
        int cum = 0;
        for (int s = 0; s < NSEG; ++s) {
            if (t == cum) isS = true;
            cum += vid_lens[s];
            if (t == cum - 1) isE = true;
        }
    }
    const bool tapAct[3] = {!isS, true, !isE};

    auto stage = [&](int s) {
        int tap = s >> 1, kp = s & 1;
        if (!tapAct[tap]) return;
        int tp = t + tap - 1;
        const char* yb = (const char*)yT + (size_t)tp * HWP * 256;
        char* buf = ldsT + (s & 1) * 14336;
#pragma unroll
        for (int r = 0; r < 4; ++r) {
            int c = r * 256 + wid * 64 + l;
            if (r < 3 || wid < 2) {                    // c < 896, wave-uniform
                int px = c >> 3, sp = c & 7;
                int ssrc = sp ^ (px & 7);
                const char* g = yb + ((size_t)(chunk * 112 + px)) * 256 + kp * 128 + ssrc * 16;
                char* ldst = buf + (r * 256 + wid * 64) * 16;
                gld_lds16(g, ldst);
            }
        }
    };

    f32x4 acc[2][7];
#pragma unroll
    for (int m = 0; m < 2; ++m)
#pragma unroll
        for (int n = 0; n < 7; ++n) acc[m][n] = (f32x4){0.f, 0.f, 0.f, 0.f};

    const bf16x8* wAv = (const bf16x8*)wAt;

    stage(0);
    __syncthreads();

    for (int s = 0; s < 6; ++s) {
        if (s < 5) stage(s + 1);
        int tap = s >> 1, kp = s & 1;
        if (tapAct[tap]) {
            const char* buf = ldsT + (s & 1) * 14336;
            bf16x8 a[2][2];
#pragma unroll
            for (int m = 0; m < 2; ++m)
#pragma unroll
                for (int k1 = 0; k1 < 2; ++k1)
                    a[m][k1] = wAv[((tap * 8 + wid * 2 + m) * 4 + kp * 2 + k1) * 64 + l];
            __builtin_amdgcn_s_setprio(1);
#pragma unroll
            for (int k1 = 0; k1 < 2; ++k1) {
#pragma unroll
                for (int nf = 0; nf < 7; ++nf) {
                    int addr = (nf * 16 + l15) * 128 + ((k1 * 4 + kgrp) ^ sx) * 16;
                    i32x4 bi = *(const i32x4*)(buf + addr);
                    bf16x8 b = __builtin_bit_cast(bf16x8, bi);
                    acc[0][nf] = __builtin_amdgcn_mfma_f32_16x16x32_bf16(a[0][k1], b, acc[0][nf], 0, 0, 0);
                    acc[1][nf] = __builtin_amdgcn_mfma_f32_16x16x32_bf16(a[1][k1], b, acc[1][nf], 0, 0, 0);
                }
            }
            __builtin_amdgcn_s_setprio(0);
        }
        __syncthreads();
    }

    // ---- epilogue: LDS transpose -> coalesced bias/PReLU/residual/store ----
    float* fl = (float*)ldsT;
    const int wbase = wid * 1856;            // 16 co x 116 px-stride floats
#pragma unroll
    for (int m = 0; m < 2; ++m) {
#pragma unroll
        for (int nf = 0; nf < 7; ++nf)
#pragma unroll
            for (int rr = 0; rr < 4; ++rr)
                fl[wbase + (kgrp * 4 + rr) * 116 + nf * 16 + l15] = acc[m][nf][rr];
#pragma unroll
        for (int j = 0; j < 7; ++j) {
            int idx = j * 64 + l;
            int co_r = idx / 28, q = idx % 28;
            f32x4 v4 = *(const f32x4*)&fl[wbase + co_r * 116 + q * 4];
            int co_g = wid * 32 + m * 16 + co_r;
            float bt = b_t[co_g], al = alpha[co_g];
            size_t gi = ((size_t)(t * CH + co_g)) * HWP + chunk * 112 + q * 4;
            float4 xv = *(const float4*)&x[gi];
            float xr[4] = {xv.x, xv.y, xv.z, xv.w};
            float rrv[4];
#pragma unroll
            for (int e = 0; e < 4; ++e) {
                float v = v4[e] + bt;
                v = (v >= 0.f) ? v : al * v;
                rrv[e] = v + xr[e];
            }
            *(float4*)&out[gi] = make_float4(rrv[0], rrv[1], rrv[2], rrv[3]);
        }
        __syncthreads();   // all waves done with region before m=1 reuse
    }
}

// ---------------------------------------------------------------------------
__global__ void write_lens(const int* __restrict__ vid_lens, float* __restrict__ out) {
    int i = threadIdx.x;
    if (i < NSEG) out[NOUT + i] = (float)vid_lens[i];
}

// ---------------------------------------------------------------------------
extern "C" void kernel_launch(void* const* d_in, const int* in_sizes, int n_in,
                              void* d_out, int out_size, void* d_ws, size_t ws_size,
                              hipStream_t stream) {
    const float* x        = (const float*)d_in[0];
    const int*   vid_lens = (const int*)d_in[1];
    const float* w_sp     = (const float*)d_in[2];
    const float* b_sp     = (const float*)d_in[3];
    const float* w_t      = (const float*)d_in[4];
    const float* b_t      = (const float*)d_in[5];
    const float* alpha    = (const float*)d_in[6];
    float* out = (float*)d_out;

    unsigned short* yT = (unsigned short*)d_ws;                       // 102,760,448 B
    short* wA  = (short*)((char*)d_ws + 102760448);                   //    294,912 B
    short* wAt = (short*)((char*)d_ws + 102760448 + 294912);          //     98,304 B

    repack_wsp<<<576, 256, 0, stream>>>(w_sp, wA);
    repack_wt2<<<192, 256, 0, stream>>>(w_t, wAt);
    spatial_mfma<<<dim3(4, 512), 512, 0, stream>>>(x, wA, b_sp, yT);
    temporal_mfma<<<dim3(7, 512), 256, 0, stream>>>(yT, wAt, b_t, alpha, x, vid_lens, out);
    write_lens<<<1, 64, 0, stream>>>(vid_lens, out);
}

// Round 6
// 339.123 us; speedup vs baseline: 1.1227x; 1.1227x over previous
//
#include <hip/hip_runtime.h>

#define TT   512
#define CH   128
#define HWP  784        // 28*28
#define NSEG 8
#define NOUT 51380224   // 512*128*784

typedef short bf16x8  __attribute__((ext_vector_type(8)));
typedef float f32x4   __attribute__((ext_vector_type(4)));
typedef float f32x16  __attribute__((ext_vector_type(16)));
typedef int   i32x4   __attribute__((ext_vector_type(4)));
typedef unsigned short u16x4 __attribute__((ext_vector_type(4)));

__device__ inline unsigned short f2bf(float f) {
    unsigned u = __builtin_bit_cast(unsigned, f);
    u += 0x7fffu + ((u >> 16) & 1u);          // RNE
    return (unsigned short)(u >> 16);
}

__device__ inline void gld_lds16(const void* g, void* l) {
    __builtin_amdgcn_global_load_lds(
        (const __attribute__((address_space(1))) void*)g,
        (__attribute__((address_space(3))) void*)l, 16, 0, 0);
}

#define MFMA32(A, B, C) __builtin_amdgcn_mfma_f32_32x32x16_bf16(A, B, C, 0, 0, 0)

// ---------------------------------------------------------------------------
// Spatial weight repack for 32x32x16 MFMA, frag-major:
// frag f = tap*8+ks, block m: lane l = kgrp*32 + (co&31), elem e: ci = ks*16+kgrp*8+e
// dst = ((f*4 + m)*64 + l)*8 + e
// ---------------------------------------------------------------------------
__global__ void repack_wsp(const float* __restrict__ w, short* __restrict__ wA) {
    int s = blockIdx.x * 256 + threadIdx.x;
    if (s >= 128 * 128 * 9) return;
    int co = s / 1152, r = s % 1152, ci = r / 9, kh = (r % 9) / 3, kw = r % 3;
    int tap = kh * 3 + kw;
    int m = co >> 5, row = co & 31;
    int ks = ci >> 4, kgrp = (ci >> 3) & 1, e = ci & 7;
    int lane = kgrp * 32 + row;
    int dst = (((tap * 8 + ks) * 4 + m) * 64 + lane) * 8 + e;
    wA[dst] = (short)f2bf(w[s]);
}

// ---------------------------------------------------------------------------
// Temporal weight repack (identity ci order, 16x16x32 frag-major):
// wAt[tap][o>>4][i>>5][(i>>3)&3][o&15][i&7]
// ---------------------------------------------------------------------------
__global__ void repack_wt2(const float* __restrict__ w, short* __restrict__ wAt) {
    int s = blockIdx.x * 256 + threadIdx.x;
    if (s >= 128 * 128 * 3) return;
    int o = s / 384, r = s % 384, i = r / 3, tap = r % 3;
    int dst = tap * 16384 + (o >> 4) * 2048 + (i >> 5) * 512 +
              ((i >> 3) & 3) * 128 + (o & 15) * 8 + (i & 7);
    wAt[dst] = (short)f2bf(w[s]);
}

// ---------------------------------------------------------------------------
// Spatial 3x3 conv via mfma_f32_32x32x16_bf16. grid (4, 512), block 512.
// Block: 8 rows x 128 co. LDS window [10 rows][30 st][128 ci] bf16 with
// bijective slot swizzle slot' = slot ^ (stv&15)  (reads <=2-way, writes free).
// Waves: ch(2 co-halves: 2 co-blocks each) x pg(4 px-groups: 2 tiles of 32 px).
// Per (tap,ks): 2 A global loads (depth-2 reg prefetch), 2 ds_read_b128,
// 4 MFMAs. Epilogue: per-lane u16x4 stores (L2 merges to full lines).
// ---------------------------------------------------------------------------
__global__ __launch_bounds__(512, 4) void spatial_mfma(
    const float* __restrict__ x, const short* __restrict__ wA,
    const float* __restrict__ b_sp, unsigned short* __restrict__ yT)
{
    __shared__ __align__(16) short xs[300 * 128];   // 76800 B
    char* xsb = (char*)xs;
    const int t = blockIdx.y, blockh = blockIdx.x * 8;
    const int tid = threadIdx.x;

    // ---- zero pad columns: st = r*30 + {0,29}, r = 0..9 ----
    for (int it = 0; it < 3; ++it) {
        int u = it * 512 + tid;
        if (u < 1280) {
            int cp = u & 63, rs = u >> 6;        // rs 0..19
            int st = (rs >> 1) * 30 + (rs & 1) * 29;
            int addr = (st << 8) | (((cp >> 2) ^ (st & 15)) << 4) | ((cp & 3) << 2);
            *(unsigned*)(xsb + addr) = 0u;
        }
    }
    // ---- stage x window: lane=cp (conflict-free), wave-uniform st ----
    for (int it = 0; it < 9; ++it) {
        int u = it * 512 + tid;
        if (u < 4480) {
            int cp = u & 63, pq = u >> 6;        // pq 0..69
            int rl = pq / 7, g = pq % 7;
            int rr = blockh - 1 + rl;
            float4 f0 = make_float4(0.f, 0.f, 0.f, 0.f), f1 = f0;
            if (rr >= 0 && rr < 28) {
                const float* p0 = &x[((size_t)(t * CH + 2 * cp)) * HWP + rr * 28 + g * 4];
                f0 = *(const float4*)p0;
                f1 = *(const float4*)(p0 + HWP);
            }
            float a0[4] = {f0.x, f0.y, f0.z, f0.w}, a1[4] = {f1.x, f1.y, f1.z, f1.w};
            int stb = rl * 30 + g * 4 + 1;
#pragma unroll
            for (int j = 0; j < 4; ++j) {
                int st = stb + j;
                unsigned val = (unsigned)f2bf(a0[j]) | ((unsigned)f2bf(a1[j]) << 16);
                int addr = (st << 8) | (((cp >> 2) ^ (st & 15)) << 4) | ((cp & 3) << 2);
                *(unsigned*)(xsb + addr) = val;
            }
        }
    }
    __syncthreads();

    const int wid = tid >> 6, l = tid & 63;
    const int l31 = l & 31, bb5 = l >> 5;
    const int ch = wid & 1, pg = wid >> 1;
    int rows = 28 - blockh; if (rows > 8) rows = 8;
    const int pxcnt = rows * 28;

    const int tile0 = pg * 2, tile1 = pg * 2 + 1;
    const bool has0 = (tile0 * 32 < pxcnt);
    const bool has1 = (tile1 < 7) && (tile1 * 32 < pxcnt);
    if (!has0) return;                        // idle waves (partial last block)

    const int p_0 = tile0 * 32 + l31;
    const int p_1 = has1 ? tile1 * 32 + l31 : p_0;
    const int st0_0 = (p_0 / 28 + 1) * 30 + (p_0 % 28) + 1;
    const int st0_1 = (p_1 / 28 + 1) * 30 + (p_1 % 28) + 1;
    const bool pok0 = (p_0 < pxcnt);
    const bool pok1 = has1 && (p_1 < pxcnt);

    f32x16 zz = {};
    f32x16 acc00 = zz, acc10 = zz, acc01 = zz, acc11 = zz;   // [m][nf]

    const bf16x8* wv = (const bf16x8*)wA;
    const int ch2 = ch * 2;

    // ---- depth-2 A prefetch (named regs; frag f == flat it) ----
    bf16x8 a0A = wv[(0 * 4 + ch2) * 64 + l];
    bf16x8 a1A = wv[(0 * 4 + ch2 + 1) * 64 + l];
    bf16x8 a0B = wv[(1 * 4 + ch2) * 64 + l];
    bf16x8 a1B = wv[(1 * 4 + ch2 + 1) * 64 + l];

    for (int it = 0; it < 72; it += 2) {
        const int tap = it >> 3, ks = it & 7;   // it even -> it,it+1 same tap
        const int off = (tap / 3 - 1) * 30 + (tap % 3) - 1;
        const int stv0 = st0_0 + off, stv1 = st0_1 + off;
        const int rb0 = (stv0 << 8), sw0 = (stv0 & 15);
        const int rb1 = (stv1 << 8), sw1 = (stv1 & 15);

        i32x4 b0 = *(const i32x4*)(xsb + (rb0 | (((2 * ks + bb5) ^ sw0) << 4)));
        i32x4 c0 = *(const i32x4*)(xsb + (rb0 | (((2 * ks + 2 + bb5) ^ sw0) << 4)));
        i32x4 b1 = b0, c1 = c0;
        if (has1) {
            b1 = *(const i32x4*)(xsb + (rb1 | (((2 * ks + bb5) ^ sw1) << 4)));
            c1 = *(const i32x4*)(xsb + (rb1 | (((2 * ks + 2 + bb5) ^ sw1) << 4)));
        }
        bf16x8 fb0 = __builtin_bit_cast(bf16x8, b0);
        bf16x8 fb1 = __builtin_bit_cast(bf16x8, b1);
        bf16x8 fc0 = __builtin_bit_cast(bf16x8, c0);
        bf16x8 fc1 = __builtin_bit_cast(bf16x8, c1);

        __builtin_amdgcn_s_setprio(1);
        acc00 = MFMA32(a0A, fb0, acc00);
        acc10 = MFMA32(a1A, fb0, acc10);
        if (has1) {
            acc01 = MFMA32(a0A, fb1, acc01);
            acc11 = MFMA32(a1A, fb1, acc11);
        }
        __builtin_amdgcn_s_setprio(0);
        {   // prefetch it+2 (clamped)
            int f = (it + 2 < 72) ? it + 2 : 71;
            a0A = wv[(f * 4 + ch2) * 64 + l];
            a1A = wv[(f * 4 + ch2 + 1) * 64 + l];
        }
        __builtin_amdgcn_s_setprio(1);
        acc00 = MFMA32(a0B, fc0, acc00);
        acc10 = MFMA32(a1B, fc0, acc10);
        if (has1) {
            acc01 = MFMA32(a0B, fc1, acc01);
            acc11 = MFMA32(a1B, fc1, acc11);
        }
        __builtin_amdgcn_s_setprio(0);
        {   // prefetch it+3 (clamped)
            int f = (it + 3 < 72) ? it + 3 : 71;
            a0B = wv[(f * 4 + ch2) * 64 + l];
            a1B = wv[(f * 4 + ch2 + 1) * 64 + l];
        }
    }

    // ---- epilogue: +b_sp, u16x4 per (m, r2); lane pairs cover full lines ----
    const size_t base0 = ((size_t)t * HWP + blockh * 28 + p_0) * CH;
    const size_t base1 = ((size_t)t * HWP + blockh * 28 + p_1) * CH;
#pragma unroll
    for (int mm = 0; mm < 2; ++mm) {
        const f32x16 A0 = (mm == 0) ? acc00 : acc10;
        const f32x16 A1 = (mm == 0) ? acc01 : acc11;
#pragma unroll
        for (int r2 = 0; r2 < 4; ++r2) {
            int cb = (ch2 + mm) * 32 + 8 * r2 + 4 * bb5;
            float4 bs = *(const float4*)&b_sp[cb];
            float bsa[4] = {bs.x, bs.y, bs.z, bs.w};
            u16x4 pk0, pk1;
#pragma unroll
            for (int q = 0; q < 4; ++q) {
                pk0[q] = f2bf(A0[r2 * 4 + q] + bsa[q]);
                pk1[q] = f2bf(A1[r2 * 4 + q] + bsa[q]);
            }
            if (pok0) *(u16x4*)&yT[base0 + cb] = pk0;
            if (pok1) *(u16x4*)&yT[base1 + cb] = pk1;
        }
    }
}

// ---------------------------------------------------------------------------
// Ragged temporal conv: 4-wave blocks, async LDS-staged B, double-buffered.
// grid (7, 512), block 256. (unchanged)
// ---------------------------------------------------------------------------
__global__ __launch_bounds__(256, 4) void temporal_mfma(
    const unsigned short* __restrict__ yT, const short* __restrict__ wAt,
    const float* __restrict__ b_t, const float* __restrict__ alpha,
    const float* __restrict__ x, const int* __restrict__ vid_lens,
    float* __restrict__ out)
{
    __shared__ __align__(16) char ldsT[29696];   // 2x14336 stage | 4x7424 epi

    const int chunk = blockIdx.x, t = blockIdx.y;
    const int tid = threadIdx.x, wid = tid >> 6, l = tid & 63;
    const int l15 = l & 15, kgrp = l >> 4;
    const int sx = l15 & 7;

    bool isS = false, isE = false;
    {
        int cum = 0;
        for (int s = 0; s < NSEG; ++s) {
            if (t == cum) isS = true;
            cum += vid_lens[s];
            if (t == cum - 1) isE = true;
        }
    }
    const bool tapAct[3] = {!isS, true, !isE};

    auto stage = [&](int s) {
        int tap = s >> 1, kp = s & 1;
        if (!tapAct[tap]) return;
        int tp = t + tap - 1;
        const char* yb = (const char*)yT + (size_t)tp * HWP * 256;
        char* buf = ldsT + (s & 1) * 14336;
#pragma unroll
        for (int r = 0; r < 4; ++r) {
            int c = r * 256 + wid * 64 + l;
            if (r < 3 || wid < 2) {                    // c < 896, wave-uniform
                int px = c >> 3, sp = c & 7;
                int ssrc = sp ^ (px & 7);
                const char* g = yb + ((size_t)(chunk * 112 + px)) * 256 + kp * 128 + ssrc * 16;
                char* ldst = buf + (r * 256 + wid * 64) * 16;
                gld_lds16(g, ldst);
            }
        }
    };

    f32x4 acc[2][7];
#pragma unroll
    for (int m = 0; m < 2; ++m)
#pragma unroll
        for (int n = 0; n < 7; ++n) acc[m][n] = (f32x4){0.f, 0.f, 0.f, 0.f};

    const bf16x8* wAv = (const bf16x8*)wAt;

    stage(0);
    __syncthreads();

    for (int s = 0; s < 6; ++s) {
        if (s < 5) stage(s + 1);
        int tap = s >> 1, kp = s & 1;
        if (tapAct[tap]) {
            const char* buf = ldsT + (s & 1) * 14336;
            bf16x8 a[2][2];
#pragma unroll
            for (int m = 0; m < 2; ++m)
#pragma unroll
                for (int k1 = 0; k1 < 2; ++k1)
                    a[m][k1] = wAv[((tap * 8 + wid * 2 + m) * 4 + kp * 2 + k1) * 64 + l];
            __builtin_amdgcn_s_setprio(1);
#pragma unroll
            for (int k1 = 0; k1 < 2; ++k1) {
#pragma unroll
                for (int nf = 0; nf < 7; ++nf) {
                    int addr = (nf * 16 + l15) * 128 + ((k1 * 4 + kgrp) ^ sx) * 16;
                    i32x4 bi = *(const i32x4*)(buf + addr);
                    bf16x8 b = __builtin_bit_cast(bf16x8, bi);
                    acc[0][nf] = __builtin_amdgcn_mfma_f32_16x16x32_bf16(a[0][k1], b, acc[0][nf], 0, 0, 0);
                    acc[1][nf] = __builtin_amdgcn_mfma_f32_16x16x32_bf16(a[1][k1], b, acc[1][nf], 0, 0, 0);
                }
            }
            __builtin_amdgcn_s_setprio(0);
        }
        __syncthreads();
    }

    // ---- epilogue: LDS transpose -> coalesced bias/PReLU/residual/store ----
    float* fl = (float*)ldsT;
    const int wbase = wid * 1856;            // 16 co x 116 px-stride floats
#pragma unroll
    for (int m = 0; m < 2; ++m) {
#pragma unroll
        for (int nf = 0; nf < 7; ++nf)
#pragma unroll
            for (int rr = 0; rr < 4; ++rr)
                fl[wbase + (kgrp * 4 + rr) * 116 + nf * 16 + l15] = acc[m][nf][rr];
#pragma unroll
        for (int j = 0; j < 7; ++j) {
            int idx = j * 64 + l;
            int co_r = idx / 28, q = idx % 28;
            f32x4 v4 = *(const f32x4*)&fl[wbase + co_r * 116 + q * 4];
            int co_g = wid * 32 + m * 16 + co_r;
            float bt = b_t[co_g], al = alpha[co_g];
            size_t gi = ((size_t)(t * CH + co_g)) * HWP + chunk * 112 + q * 4;
            float4 xv = *(const float4*)&x[gi];
            float xr[4] = {xv.x, xv.y, xv.z, xv.w};
            float rrv[4];
#pragma unroll
            for (int e = 0; e < 4; ++e) {
                float v = v4[e] + bt;
                v = (v >= 0.f) ? v : al * v;
                rrv[e] = v + xr[e];
            }
            *(float4*)&out[gi] = make_float4(rrv[0], rrv[1], rrv[2], rrv[3]);
        }
        __syncthreads();   // all waves done with region before m=1 reuse
    }
}

// ---------------------------------------------------------------------------
__global__ void write_lens(const int* __restrict__ vid_lens, float* __restrict__ out) {
    int i = threadIdx.x;
    if (i < NSEG) out[NOUT + i] = (float)vid_lens[i];
}

// ---------------------------------------------------------------------------
extern "C" void kernel_launch(void* const* d_in, const int* in_sizes, int n_in,
                              void* d_out, int out_size, void* d_ws, size_t ws_size,
                              hipStream_t stream) {
    const float* x        = (const float*)d_in[0];
    const int*   vid_lens = (const int*)d_in[1];
    const float* w_sp     = (const float*)d_in[2];
    const float* b_sp     = (const float*)d_in[3];
    const float* w_t      = (const float*)d_in[4];
    const float* b_t      = (const float*)d_in[5];
    const float* alpha    = (const float*)d_in[6];
    float* out = (float*)d_out;

    unsigned short* yT = (unsigned short*)d_ws;                       // 102,760,448 B
    short* wA  = (short*)((char*)d_ws + 102760448);                   //    294,912 B
    short* wAt = (short*)((char*)d_ws + 102760448 + 294912);          //     98,304 B

    repack_wsp<<<576, 256, 0, stream>>>(w_sp, wA);
    repack_wt2<<<192, 256, 0, stream>>>(w_t, wAt);
    spatial_mfma<<<dim3(4, 512), 512, 0, stream>>>(x, wA, b_sp, yT);
    temporal_mfma<<<dim3(7, 512), 256, 0, stream>>>(yT, wAt, b_t, alpha, x, vid_lens, out);
    write_lens<<<1, 64, 0, stream>>>(vid_lens, out);
}